// Round 4
// baseline (149.952 us; speedup 1.0000x reference)
//
#include <hip/hip_runtime.h>

#define HH 128
#define WW 128
#define BB 64
#define OO 32
#define LP2 130   // float2 pitch: 130*8=1040B rows -> every row 16B-aligned

// Row-pair texture layout: img2[y][x] = (I[y][x], I[y+1][x]) for y=0..126.
// All 4 bilinear taps of a pixel are img2[idx] and img2[idx+1] -> ONE
// ds_read2_b64 per pixel (was two ds_read2_b32). Bytes/pixel unchanged (16B),
// DS instruction count halved; 8B elements put the 64-lane access at the LDS
// 128B/cyc floor in both rotated and unrotated regimes (4 lanes/bank = floor).
// LDS: 127*130*8 = 132080 B -> 1 block/CU (R3 showed 16 waves/CU is enough).
// Round-1..3 established: occupancy (32 vs 16 waves), VGPR cap (64 vs 128),
// and bank pitch are all non-binding; DS issue is the last invariant pipe.
// Coordinate clamp into [0, 126.99999] replaces the reference's index clamp
// (equivalent within ~1e-5 tap weight; keeps the +1 taps in-bounds).
__launch_bounds__(1024, 4)
__global__ void sample_kernel(const float* __restrict__ X,
                              const float* __restrict__ eps,
                              const float* __restrict__ tmin,
                              const float* __restrict__ tmax,
                              float* __restrict__ out) {
    __shared__ float2 img2[127 * LP2];   // 132080 B
    __shared__ float scoef[4][6];

    const int bid = blockIdx.x;
    const int og  = bid & 7;          // consecutive blocks share b -> L2 reuse
    const int b   = bid >> 3;
    const int tid = threadIdx.x;

    if (tid < 4) {
        const int o = og * 4 + tid;
        float th[7];
#pragma unroll
        for (int i = 0; i < 7; ++i) {
            const float mn = tmin[i], mx = tmax[i];
            th[i] = mn + (mx - mn) * eps[o * 7 + i];
        }
        const float ang = th[0], sx = th[1], sy = th[2], px = th[3],
                    py = th[4], tx = th[5], ty = th[6];
        const float c = cosf(ang), s = sinf(ang);
        const float half = 0.5f * (WW - 1);  // 63.5
        scoef[tid][0] = (c * sx - s * py) * half;   // cx0
        scoef[tid][1] = (c * px - s * sy) * half;   // cx1
        scoef[tid][2] = (tx + 1.0f) * half;         // cxt
        scoef[tid][3] = (s * sx + c * py) * half;   // cy0
        scoef[tid][4] = (s * px + c * sy) * half;   // cy1
        scoef[tid][5] = (ty + 1.0f) * half;         // cyt
    }

    // Stage row-pairs: for y=0..126, float4 of row y and row y+1, interleaved
    // into 4 consecutive float2 (16B-aligned -> 2x ds_write_b128). Row y is
    // loaded twice across pairs -> second read is L1/L2-hit. 127*32 = 4064 items.
    {
        const float4* __restrict__ src4 = (const float4*)(X + b * (HH * WW));
#pragma unroll
        for (int i = 0; i < 4; ++i) {
            const int g = tid + i * 1024;
            if (g < 127 * 32) {
                const int y  = g >> 5;
                const int x4 = g & 31;
                const float4 a = src4[(y << 5) + x4];        // row y
                const float4 c = src4[(y << 5) + 32 + x4];   // row y+1
                float2* __restrict__ d = &img2[y * LP2 + (x4 << 2)];
                d[0] = make_float2(a.x, c.x);
                d[1] = make_float2(a.y, c.y);
                d[2] = make_float2(a.z, c.z);
                d[3] = make_float2(a.w, c.w);
            }
        }
    }
    __syncthreads();

    const int w  = tid & (WW - 1);
    const int h0 = tid >> 7;                 // 0..7; wave = 256B-contiguous row chunk
    const float step  = 2.0f / 127.0f;
    const float hstep = 8.0f * step;         // row stride of the i-loop
    const float Xg  = -1.0f + w * step;
    const float Yg0 = -1.0f + h0 * step;
    const float hi  = 126.999992f;           // nextbelow(127)

#pragma unroll
    for (int j = 0; j < 4; ++j) {
        const int o = og * 4 + j;
        const float cx0 = scoef[j][0];
        const float cx1 = scoef[j][1];
        const float cxt = scoef[j][2];
        const float cy0 = scoef[j][3];
        const float cy1 = scoef[j][4];
        const float cyt = scoef[j][5];

        float x = fmaf(cx1, Yg0, fmaf(cx0, Xg, cxt));
        float y = fmaf(cy1, Yg0, fmaf(cy0, Xg, cyt));
        const float dx = cx1 * hstep;
        const float dy = cy1 * hstep;

        float* __restrict__ outp =
            out + ((size_t)(o * BB + b) * (HH * WW)) + h0 * WW + w;

#pragma unroll 8
        for (int i = 0; i < 16; ++i) {
            const float xc = __builtin_amdgcn_fmed3f(x, 0.0f, hi);
            const float yc = __builtin_amdgcn_fmed3f(y, 0.0f, hi);
            const float x0f = floorf(xc);
            const float y0f = floorf(yc);
            const float wx = xc - x0f;
            const float wy = yc - y0f;
            const int idx = (int)fmaf(y0f, (float)LP2, x0f);  // exact (< 2^24)

            const float2 p0 = img2[idx];       // (Ia, Ib): rows y0, y0+1 at x0
            const float2 p1 = img2[idx + 1];   // (Ic, Id): rows y0, y0+1 at x0+1
                                               // -> one ds_read2_b64 (off 0,1)
            const float top = fmaf(wx, p1.x - p0.x, p0.x);
            const float bot = fmaf(wx, p1.y - p0.y, p0.y);
            *outp = fmaf(wy, bot - top, top);

            outp += 8 * WW;
            x += dx;
            y += dy;
        }
    }
}

extern "C" void kernel_launch(void* const* d_in, const int* in_sizes, int n_in,
                              void* d_out, int out_size, void* d_ws, size_t ws_size,
                              hipStream_t stream) {
    const float* X    = (const float*)d_in[0];
    const float* eps  = (const float*)d_in[1];
    const float* tmin = (const float*)d_in[2];
    const float* tmax = (const float*)d_in[3];
    float* out = (float*)d_out;

    const int nblocks = BB * 8;  // 512: 1 resident/CU (LDS-capped), 2 sequential
    sample_kernel<<<nblocks, 1024, 0, stream>>>(X, eps, tmin, tmax, out);
}